// Round 1
// baseline (100.504 us; speedup 1.0000x reference)
//
#include <hip/hip_runtime.h>

#define NB 8
#define NS 1024
#define NH 8
#define NMONO 56    // monomials (a,b,c), a+b+c <= 5, graded order

// ---------------------------------------------------------------------------
// R13: SINGLE fused kernel, workspace-free.
// Quantum layer collapsed analytically (verified R3-R11): c_j = cos(x_j+th_j),
//   q = (prod c1..c7, c0c1, c0c1c2)/8, k = (c0..c3, c0..c4, c0..c5),
//   v = (c0..c6, c0..c7).  Linear attention via deg-5 Taylor of e^{q.k}
//   (|q.k|<=0.375, rel err 8e-6): moments M_ch[i] = sum_t mono_i(k) * w_t,
//   w in {1, v0, v1}; att = phi(q).M_v / phi(q).M_1.
// Rationale: rocprof shows remaining time is node overhead (~5-9us/node) plus
//   a 256MiB/40us harness ws-poison fill -- NOT kernel compute.  The 2-kernel
//   split existed only for the cross-block t-reduction; this version accepts
//   x32 redundant moment computation (each block recomputes its b's moments:
//   ~4.2k VALU ops/thread, ~9us issue-bound) to get ONE launch node and zero
//   workspace use.  All 3 channels accumulated per thread (monomials shared:
//   55 mul + 56 add + 112 fma per row) -- cheaper than 3 channel-waves.
// Grid: 256 blocks = (b = bid>>5, 32-s chunk = bid&31), 1 block/CU.
// Block: 512 threads = 8 waves; thread = (h = tid&7, tslot = tid>>3),
//   16 rows each (t = tslot + 64i).  Reduce: butterfly shfl_xor over the 8
//   same-h lanes (xor 8/16/32), then LDS combine across the 8 waves.
// ---------------------------------------------------------------------------

// graded enumeration; mono[i] = mono[PRED[i]] * k[VARI[i]] (PRED folds at CT)
constexpr int PRED[NMONO] = {
    0,
    0, 0, 0,
    1, 2, 3, 2, 3, 3,
    4, 5, 6, 7, 8, 9, 7, 8, 9, 9,
    10,11,12,13,14,15,16,17,18,19,16,17,18,19,19,
    20,21,22,23,24,25,26,27,28,29,30,31,32,33,34,30,31,32,33,34,34};
constexpr int VARI[NMONO] = {
    0,
    0, 1, 2,
    0, 0, 0, 1, 1, 2,
    0, 0, 0, 0, 0, 0, 1, 1, 1, 2,
    0, 0, 0, 0, 0, 0, 0, 0, 0, 0, 1, 1, 1, 1, 2,
    0, 0, 0, 0, 0, 0, 0, 0, 0, 0, 0, 0, 0, 0, 0, 1, 1, 1, 1, 1, 2};
#define F6 0.166666666666667f
#define F12 0.0833333333333333f
#define F24 0.0416666666666667f
#define F120 0.00833333333333333f
constexpr float COEF[NMONO] = {          // 1/(a! b! c!)
    1.f,
    1.f, 1.f, 1.f,
    0.5f, 1.f, 1.f, 0.5f, 1.f, 0.5f,
    F6, 0.5f, 0.5f, 0.5f, 1.f, 0.5f, F6, 0.5f, 0.5f, F6,
    F24, F6, F6, 0.25f, 0.5f, 0.25f, F6, 0.5f, 0.5f, F6, F24, F6, 0.25f, F6, F24,
    F120, F24, F24, F12, F6, F12, F12, 0.25f, 0.25f, F12, F24, F6, 0.25f, F6, F24,
    F120, F24, F12, F12, F24, F120};

__global__ __launch_bounds__(512, 2) void fused_qattn_kernel(
        const float* __restrict__ x, const float* __restrict__ theta,
        const float* __restrict__ W, const float* __restrict__ bias,
        float* __restrict__ out) {
    __shared__ __align__(16) float redL[8][8][168];   // [wave][h][ch*56+i] 43 KB
    __shared__ __align__(16) float MhL[8 * 172];      // [h][ch*56+i], padded
    __shared__ float WtL[16 * 65];
    __shared__ float biasL[64];
    __shared__ float attL[32][17];

    const int tid = threadIdx.x;
    const int b = blockIdx.x >> 5;
    const int chunk = blockIdx.x & 31;
    const int s0 = chunk * 32;

    float th[8];
#pragma unroll
    for (int j = 0; j < 8; ++j) th[j] = theta[j];

    // stage projection weights (consumed after 2 barriers in phase C)
    for (int i = tid; i < 1024; i += 512) WtL[(i & 15) * 65 + (i >> 4)] = W[i];
    if (tid < 64) biasL[tid] = bias[tid];

    // ---- phase A: moments (redundant per chunk; 8192 rows / 512 threads) ----
    const int h = tid & 7;
    const int tslot = tid >> 3;                       // 0..63

    float accS[NMONO], accA[NMONO], accB[NMONO];
#pragma unroll
    for (int i = 0; i < NMONO; ++i) { accS[i] = 0.f; accA[i] = 0.f; accB[i] = 0.f; }

#pragma unroll 1
    for (int it = 0; it < 16; ++it) {
        const int t = tslot + 64 * it;
        const float4* xp = (const float4*)(x + ((size_t)(b * NS + t)) * 64 + h * 8);
        float4 lo = xp[0], hi = xp[1];
        float c0 = __cosf(lo.x + th[0]);
        float c1 = __cosf(lo.y + th[1]);
        float c2 = __cosf(lo.z + th[2]);
        float c3 = __cosf(lo.w + th[3]);
        float c4 = __cosf(hi.x + th[4]);
        float c5 = __cosf(hi.y + th[5]);
        float c6 = __cosf(hi.z + th[6]);
        float c7 = __cosf(hi.w + th[7]);
        float k0 = ((c0 * c1) * c2) * c3;
        float k1 = k0 * c4;
        float k2 = k1 * c5;
        float v0 = k2 * c6;
        float v1 = v0 * c7;

        float mono[NMONO];
        mono[0] = 1.f;
        accS[0] += 1.f;
        accA[0] += v0;
        accB[0] += v1;
#pragma unroll
        for (int i = 1; i < NMONO; ++i) {
            float var = (VARI[i] == 0) ? k0 : ((VARI[i] == 1) ? k1 : k2);
            mono[i] = mono[PRED[i]] * var;            // PRED[i] folds to literal
            accS[i] += mono[i];
            accA[i] = fmaf(mono[i], v0, accA[i]);
            accB[i] = fmaf(mono[i], v1, accB[i]);
        }
    }

    // butterfly reduce over same-h lanes (spaced 8 apart: lane bits 3,4,5)
#pragma unroll
    for (int i = 0; i < NMONO; ++i) {
        float a = accS[i];
        a += __shfl_xor(a, 8); a += __shfl_xor(a, 16); a += __shfl_xor(a, 32);
        accS[i] = a;
        float p = accA[i];
        p += __shfl_xor(p, 8); p += __shfl_xor(p, 16); p += __shfl_xor(p, 32);
        accA[i] = p;
        float q = accB[i];
        q += __shfl_xor(q, 8); q += __shfl_xor(q, 16); q += __shfl_xor(q, 32);
        accB[i] = q;
    }

    const int wv = tid >> 6;                          // wave 0..7
    const int l  = tid & 63;
    if (l < 8) {                                      // l == h here
        float* dst = &redL[wv][l][0];
#pragma unroll
        for (int g = 0; g < 14; ++g)
            ((float4*)dst)[g] = make_float4(accS[4*g], accS[4*g+1], accS[4*g+2], accS[4*g+3]);
#pragma unroll
        for (int g = 0; g < 14; ++g)
            ((float4*)(dst + 56))[g] = make_float4(accA[4*g], accA[4*g+1], accA[4*g+2], accA[4*g+3]);
#pragma unroll
        for (int g = 0; g < 14; ++g)
            ((float4*)(dst + 112))[g] = make_float4(accB[4*g], accB[4*g+1], accB[4*g+2], accB[4*g+3]);
    }
    __syncthreads();

    // combine across the 8 waves, fold COEF
    for (int e = tid; e < 8 * 168; e += 512) {
        const int hh = e / 168, j = e - hh * 168;
        float s = 0.f;
#pragma unroll
        for (int ww = 0; ww < 8; ++ww) s += redL[ww][hh][j];
        MhL[hh * 172 + j] = s * COEF[j % 56];
    }
    __syncthreads();

    // ---- phase B: eval 32 s x 8 h rows via 56-dim linear attention ----
    if (tid < 256) {
        const int eh = tid >> 5, sl = tid & 31;
        const int s = s0 + sl;
        const float4* xp = (const float4*)(x + ((size_t)(b * NS + s)) * 64 + eh * 8);
        float4 lo = xp[0], hi = xp[1];
        float c0 = __cosf(lo.x + th[0]);
        float c1 = __cosf(lo.y + th[1]);
        float c2 = __cosf(lo.z + th[2]);
        float c3 = __cosf(lo.w + th[3]);
        float c4 = __cosf(hi.x + th[4]);
        float c5 = __cosf(hi.y + th[5]);
        float c6 = __cosf(hi.z + th[6]);
        float c7 = __cosf(hi.w + th[7]);
        float m1 = c0 * c1;
        float m2 = m1 * c2;
        float m0 = ((c1 * c2) * (c3 * c4)) * ((c5 * c6) * c7);
        float q0 = m0 * 0.125f, q1 = m1 * 0.125f, q2 = m2 * 0.125f;

        float mono[NMONO];
        mono[0] = 1.f;
#pragma unroll
        for (int i = 1; i < NMONO; ++i)
            mono[i] = mono[PRED[i]] * ((VARI[i] == 0) ? q0 : ((VARI[i] == 1) ? q1 : q2));

        const float4* MS = (const float4*)&MhL[eh * 172];
        const float4* MA = (const float4*)&MhL[eh * 172 + 56];
        const float4* MB = (const float4*)&MhL[eh * 172 + 112];
        float aS = 0.f, aA = 0.f, aB = 0.f;
#pragma unroll
        for (int g = 0; g < 14; ++g) {
            float4 ms = MS[g], ma = MA[g], mb = MB[g];
            float p0 = mono[g * 4 + 0], p1 = mono[g * 4 + 1];
            float p2 = mono[g * 4 + 2], p3 = mono[g * 4 + 3];
            aS = fmaf(p0, ms.x, aS); aS = fmaf(p1, ms.y, aS);
            aS = fmaf(p2, ms.z, aS); aS = fmaf(p3, ms.w, aS);
            aA = fmaf(p0, ma.x, aA); aA = fmaf(p1, ma.y, aA);
            aA = fmaf(p2, ma.z, aA); aA = fmaf(p3, ma.w, aA);
            aB = fmaf(p0, mb.x, aB); aB = fmaf(p1, mb.y, aB);
            aB = fmaf(p2, mb.z, aB); aB = fmaf(p3, mb.w, aB);
        }
        float inv = 1.0f / aS;
        attL[sl][2 * eh]     = aA * inv;
        attL[sl][2 * eh + 1] = aB * inv;
    }
    __syncthreads();

    // ---- phase C: projection (32,16) @ W^T + bias -> (32,64) ----
    {
        const int e = tid & 63, r0 = tid >> 6;        // r0 0..7
#pragma unroll
        for (int j = 0; j < 4; ++j) {
            const int row = r0 + 8 * j;               // covers 0..31
            float acc = biasL[e];
#pragma unroll
            for (int jj = 0; jj < 16; ++jj)
                acc = fmaf(attL[row][jj], WtL[jj * 65 + e], acc);
            out[((size_t)(b * NS + s0 + row)) * 64 + e] = acc;
        }
    }
}

extern "C" void kernel_launch(void* const* d_in, const int* in_sizes, int n_in,
                              void* d_out, int out_size, void* d_ws, size_t ws_size,
                              hipStream_t stream) {
    const float* x     = (const float*)d_in[0];
    const float* theta = (const float*)d_in[1];
    const float* W     = (const float*)d_in[2];
    const float* bias  = (const float*)d_in[3];
    float* out = (float*)d_out;

    // one node, no workspace: 256 blocks (= 8 b x 32 s-chunks), 1 block/CU
    fused_qattn_kernel<<<dim3(NB * 32), dim3(512), 0, stream>>>(x, theta, W, bias, out);
}

// Round 2
// 99.993 us; speedup vs baseline: 1.0051x; 1.0051x over previous
//
#include <hip/hip_runtime.h>

#define NB 8
#define NS 1024
#define NH 8
#define NMONO 56    // monomials (a,b,c), a+b+c <= 5, graded order

// ---------------------------------------------------------------------------
// R14: single fused kernel, workspace-free, SPILL FIX.
// Quantum layer collapsed analytically (verified R3-R11): c_j = cos(x_j+th_j),
//   q = (prod c1..c7, c0c1, c0c1c2)/8, k = (c0..c3, c0..c4, c0..c5),
//   v = (c0..c6, c0..c7).  Linear attention via deg-5 Taylor of e^{q.k}
//   (|q.k|<=0.375, rel err 8e-6): moments M_ch[i] = sum_t mono_i(k) * w_t,
//   w in {1, v0, v1}; att = phi(q).M_v / phi(q).M_1.
// R13 post-mortem: __launch_bounds__(512,2) was interpreted as 2 blocks/CU
//   -> 4 waves/EU -> 128-VGPR cap, but phase A needs ~230 live regs
//   (3x56 acc + ~36 live monomials).  Result: 45 MB scratch spill/dispatch
//   (WRITE_SIZE 47 MB vs 2 MB output), kernel 44 us at VALUBusy 24%.
// R14 fix: __launch_bounds__(512, 1) -> 1 block/CU, 2 waves/EU, 256-VGPR
//   cap -> no spill.  Everything else unchanged to isolate the effect.
// Grid: 256 blocks = (b = bid>>5, 32-s chunk = bid&31), 1 block/CU.
// Block: 512 threads = 8 waves; thread = (h = tid&7, tslot = tid>>3),
//   16 rows each (t = tslot + 64i).  Reduce: butterfly shfl_xor over the 8
//   same-h lanes (xor 8/16/32), then LDS combine across the 8 waves.
// Known-fixed cost outside our control: harness poisons the 256 MiB
//   workspace with a ~44 us fillBuffer INSIDE the timed window each iter.
// ---------------------------------------------------------------------------

// graded enumeration; mono[i] = mono[PRED[i]] * k[VARI[i]] (PRED folds at CT)
constexpr int PRED[NMONO] = {
    0,
    0, 0, 0,
    1, 2, 3, 2, 3, 3,
    4, 5, 6, 7, 8, 9, 7, 8, 9, 9,
    10,11,12,13,14,15,16,17,18,19,16,17,18,19,19,
    20,21,22,23,24,25,26,27,28,29,30,31,32,33,34,30,31,32,33,34,34};
constexpr int VARI[NMONO] = {
    0,
    0, 1, 2,
    0, 0, 0, 1, 1, 2,
    0, 0, 0, 0, 0, 0, 1, 1, 1, 2,
    0, 0, 0, 0, 0, 0, 0, 0, 0, 0, 1, 1, 1, 1, 2,
    0, 0, 0, 0, 0, 0, 0, 0, 0, 0, 0, 0, 0, 0, 0, 1, 1, 1, 1, 1, 2};
#define F6 0.166666666666667f
#define F12 0.0833333333333333f
#define F24 0.0416666666666667f
#define F120 0.00833333333333333f
constexpr float COEF[NMONO] = {          // 1/(a! b! c!)
    1.f,
    1.f, 1.f, 1.f,
    0.5f, 1.f, 1.f, 0.5f, 1.f, 0.5f,
    F6, 0.5f, 0.5f, 0.5f, 1.f, 0.5f, F6, 0.5f, 0.5f, F6,
    F24, F6, F6, 0.25f, 0.5f, 0.25f, F6, 0.5f, 0.5f, F6, F24, F6, 0.25f, F6, F24,
    F120, F24, F24, F12, F6, F12, F12, 0.25f, 0.25f, F12, F24, F6, 0.25f, F6, F24,
    F120, F24, F12, F12, F24, F120};

__global__ __launch_bounds__(512, 1) void fused_qattn_kernel(
        const float* __restrict__ x, const float* __restrict__ theta,
        const float* __restrict__ W, const float* __restrict__ bias,
        float* __restrict__ out) {
    __shared__ __align__(16) float redL[8][8][168];   // [wave][h][ch*56+i] 43 KB
    __shared__ __align__(16) float MhL[8 * 172];      // [h][ch*56+i], padded
    __shared__ float WtL[16 * 65];
    __shared__ float biasL[64];
    __shared__ float attL[32][17];

    const int tid = threadIdx.x;
    const int b = blockIdx.x >> 5;
    const int chunk = blockIdx.x & 31;
    const int s0 = chunk * 32;

    float th[8];
#pragma unroll
    for (int j = 0; j < 8; ++j) th[j] = theta[j];

    // stage projection weights (consumed after 2 barriers in phase C)
    for (int i = tid; i < 1024; i += 512) WtL[(i & 15) * 65 + (i >> 4)] = W[i];
    if (tid < 64) biasL[tid] = bias[tid];

    // ---- phase A: moments (redundant per chunk; 8192 rows / 512 threads) ----
    const int h = tid & 7;
    const int tslot = tid >> 3;                       // 0..63

    float accS[NMONO], accA[NMONO], accB[NMONO];
#pragma unroll
    for (int i = 0; i < NMONO; ++i) { accS[i] = 0.f; accA[i] = 0.f; accB[i] = 0.f; }

#pragma unroll 1
    for (int it = 0; it < 16; ++it) {
        const int t = tslot + 64 * it;
        const float4* xp = (const float4*)(x + ((size_t)(b * NS + t)) * 64 + h * 8);
        float4 lo = xp[0], hi = xp[1];
        float c0 = __cosf(lo.x + th[0]);
        float c1 = __cosf(lo.y + th[1]);
        float c2 = __cosf(lo.z + th[2]);
        float c3 = __cosf(lo.w + th[3]);
        float c4 = __cosf(hi.x + th[4]);
        float c5 = __cosf(hi.y + th[5]);
        float c6 = __cosf(hi.z + th[6]);
        float c7 = __cosf(hi.w + th[7]);
        float k0 = ((c0 * c1) * c2) * c3;
        float k1 = k0 * c4;
        float k2 = k1 * c5;
        float v0 = k2 * c6;
        float v1 = v0 * c7;

        float mono[NMONO];
        mono[0] = 1.f;
        accS[0] += 1.f;
        accA[0] += v0;
        accB[0] += v1;
#pragma unroll
        for (int i = 1; i < NMONO; ++i) {
            float var = (VARI[i] == 0) ? k0 : ((VARI[i] == 1) ? k1 : k2);
            mono[i] = mono[PRED[i]] * var;            // PRED[i] folds to literal
            accS[i] += mono[i];
            accA[i] = fmaf(mono[i], v0, accA[i]);
            accB[i] = fmaf(mono[i], v1, accB[i]);
        }
    }

    // butterfly reduce over same-h lanes (spaced 8 apart: lane bits 3,4,5)
#pragma unroll
    for (int i = 0; i < NMONO; ++i) {
        float a = accS[i];
        a += __shfl_xor(a, 8); a += __shfl_xor(a, 16); a += __shfl_xor(a, 32);
        accS[i] = a;
        float p = accA[i];
        p += __shfl_xor(p, 8); p += __shfl_xor(p, 16); p += __shfl_xor(p, 32);
        accA[i] = p;
        float q = accB[i];
        q += __shfl_xor(q, 8); q += __shfl_xor(q, 16); q += __shfl_xor(q, 32);
        accB[i] = q;
    }

    const int wv = tid >> 6;                          // wave 0..7
    const int l  = tid & 63;
    if (l < 8) {                                      // l == h here
        float* dst = &redL[wv][l][0];
#pragma unroll
        for (int g = 0; g < 14; ++g)
            ((float4*)dst)[g] = make_float4(accS[4*g], accS[4*g+1], accS[4*g+2], accS[4*g+3]);
#pragma unroll
        for (int g = 0; g < 14; ++g)
            ((float4*)(dst + 56))[g] = make_float4(accA[4*g], accA[4*g+1], accA[4*g+2], accA[4*g+3]);
#pragma unroll
        for (int g = 0; g < 14; ++g)
            ((float4*)(dst + 112))[g] = make_float4(accB[4*g], accB[4*g+1], accB[4*g+2], accB[4*g+3]);
    }
    __syncthreads();

    // combine across the 8 waves, fold COEF
    for (int e = tid; e < 8 * 168; e += 512) {
        const int hh = e / 168, j = e - hh * 168;
        float s = 0.f;
#pragma unroll
        for (int ww = 0; ww < 8; ++ww) s += redL[ww][hh][j];
        MhL[hh * 172 + j] = s * COEF[j % 56];
    }
    __syncthreads();

    // ---- phase B: eval 32 s x 8 h rows via 56-dim linear attention ----
    if (tid < 256) {
        const int eh = tid >> 5, sl = tid & 31;
        const int s = s0 + sl;
        const float4* xp = (const float4*)(x + ((size_t)(b * NS + s)) * 64 + eh * 8);
        float4 lo = xp[0], hi = xp[1];
        float c0 = __cosf(lo.x + th[0]);
        float c1 = __cosf(lo.y + th[1]);
        float c2 = __cosf(lo.z + th[2]);
        float c3 = __cosf(lo.w + th[3]);
        float c4 = __cosf(hi.x + th[4]);
        float c5 = __cosf(hi.y + th[5]);
        float c6 = __cosf(hi.z + th[6]);
        float c7 = __cosf(hi.w + th[7]);
        float m1 = c0 * c1;
        float m2 = m1 * c2;
        float m0 = ((c1 * c2) * (c3 * c4)) * ((c5 * c6) * c7);
        float q0 = m0 * 0.125f, q1 = m1 * 0.125f, q2 = m2 * 0.125f;

        float mono[NMONO];
        mono[0] = 1.f;
#pragma unroll
        for (int i = 1; i < NMONO; ++i)
            mono[i] = mono[PRED[i]] * ((VARI[i] == 0) ? q0 : ((VARI[i] == 1) ? q1 : q2));

        const float4* MS = (const float4*)&MhL[eh * 172];
        const float4* MA = (const float4*)&MhL[eh * 172 + 56];
        const float4* MB = (const float4*)&MhL[eh * 172 + 112];
        float aS = 0.f, aA = 0.f, aB = 0.f;
#pragma unroll
        for (int g = 0; g < 14; ++g) {
            float4 ms = MS[g], ma = MA[g], mb = MB[g];
            float p0 = mono[g * 4 + 0], p1 = mono[g * 4 + 1];
            float p2 = mono[g * 4 + 2], p3 = mono[g * 4 + 3];
            aS = fmaf(p0, ms.x, aS); aS = fmaf(p1, ms.y, aS);
            aS = fmaf(p2, ms.z, aS); aS = fmaf(p3, ms.w, aS);
            aA = fmaf(p0, ma.x, aA); aA = fmaf(p1, ma.y, aA);
            aA = fmaf(p2, ma.z, aA); aA = fmaf(p3, ma.w, aA);
            aB = fmaf(p0, mb.x, aB); aB = fmaf(p1, mb.y, aB);
            aB = fmaf(p2, mb.z, aB); aB = fmaf(p3, mb.w, aB);
        }
        float inv = 1.0f / aS;
        attL[sl][2 * eh]     = aA * inv;
        attL[sl][2 * eh + 1] = aB * inv;
    }
    __syncthreads();

    // ---- phase C: projection (32,16) @ W^T + bias -> (32,64) ----
    {
        const int e = tid & 63, r0 = tid >> 6;        // r0 0..7
#pragma unroll
        for (int j = 0; j < 4; ++j) {
            const int row = r0 + 8 * j;               // covers 0..31
            float acc = biasL[e];
#pragma unroll
            for (int jj = 0; jj < 16; ++jj)
                acc = fmaf(attL[row][jj], WtL[jj * 65 + e], acc);
            out[((size_t)(b * NS + s0 + row)) * 64 + e] = acc;
        }
    }
}

extern "C" void kernel_launch(void* const* d_in, const int* in_sizes, int n_in,
                              void* d_out, int out_size, void* d_ws, size_t ws_size,
                              hipStream_t stream) {
    const float* x     = (const float*)d_in[0];
    const float* theta = (const float*)d_in[1];
    const float* W     = (const float*)d_in[2];
    const float* bias  = (const float*)d_in[3];
    float* out = (float*)d_out;

    // one node, no workspace: 256 blocks (= 8 b x 32 s-chunks), 1 block/CU
    fused_qattn_kernel<<<dim3(NB * 32), dim3(512), 0, stream>>>(x, theta, W, bias, out);
}

// Round 3
// 99.849 us; speedup vs baseline: 1.0066x; 1.0014x over previous
//
#include <hip/hip_runtime.h>

#define NB 8
#define NS 1024
#define NH 8
#define NMONO 56    // monomials (a,b,c), a+b+c <= 5, graded order

// ---------------------------------------------------------------------------
// R15: single fused kernel, workspace-free, VGPR-BUDGET FIX (2nd attempt).
// Quantum layer collapsed analytically (verified R3-R11): c_j = cos(x_j+th_j),
//   q = (prod c1..c7, c0c1, c0c1c2)/8, k = (c0..c3, c0..c4, c0..c5),
//   v = (c0..c6, c0..c7).  Linear attention via deg-5 Taylor of e^{q.k}
//   (|q.k|<=0.375, rel err 8e-6): moments M_ch[i] = sum_t mono_i(k) * w_t,
//   w in {1, v0, v1}; att = phi(q).M_v / phi(q).M_1.
// R13/R14 post-mortem: VGPR_Count=128 under BOTH launch_bounds(512,2) and
//   (512,1) -> the 2nd arg is not the lever.  128 = 512/4 waves/EU, and
//   4 waves/EU is exactly the occupancy our 55.3 KB LDS allows (2 blocks/CU).
//   Theory: RA budgets VGPRs to the LDS-achievable occupancy, spilling the
//   ~230-reg live set (3x56 acc + ~35 monomials) -> 45 MB scratch traffic
//   per dispatch (WRITE_SIZE 47 MB vs 2 MB output), kernel 51 us.
// R15 fix: pad static LDS to ~83 KB so only 1 block/CU fits -> 2 waves/EU
//   -> 256-VGPR budget.  Also state it explicitly via amdgpu_waves_per_eu(2,2).
//   We already launch exactly 1 block/CU (grid 256), so padding is free.
// Grid: 256 blocks = (b = bid>>5, 32-s chunk = bid&31), 1 block/CU.
// Block: 512 threads = 8 waves; thread = (h = tid&7, tslot = tid>>3),
//   16 rows each (t = tslot + 64i).  Reduce: butterfly shfl_xor over the 8
//   same-h lanes (xor 8/16/32), then LDS combine across the 8 waves.
// Known-fixed cost outside our control: harness poisons the 256 MiB
//   workspace with a ~44 us fillBuffer INSIDE the timed window each iter.
// ---------------------------------------------------------------------------

// graded enumeration; mono[i] = mono[PRED[i]] * k[VARI[i]] (PRED folds at CT)
constexpr int PRED[NMONO] = {
    0,
    0, 0, 0,
    1, 2, 3, 2, 3, 3,
    4, 5, 6, 7, 8, 9, 7, 8, 9, 9,
    10,11,12,13,14,15,16,17,18,19,16,17,18,19,19,
    20,21,22,23,24,25,26,27,28,29,30,31,32,33,34,30,31,32,33,34,34};
constexpr int VARI[NMONO] = {
    0,
    0, 1, 2,
    0, 0, 0, 1, 1, 2,
    0, 0, 0, 0, 0, 0, 1, 1, 1, 2,
    0, 0, 0, 0, 0, 0, 0, 0, 0, 0, 1, 1, 1, 1, 2,
    0, 0, 0, 0, 0, 0, 0, 0, 0, 0, 0, 0, 0, 0, 0, 1, 1, 1, 1, 1, 2};
#define F6 0.166666666666667f
#define F12 0.0833333333333333f
#define F24 0.0416666666666667f
#define F120 0.00833333333333333f
constexpr float COEF[NMONO] = {          // 1/(a! b! c!)
    1.f,
    1.f, 1.f, 1.f,
    0.5f, 1.f, 1.f, 0.5f, 1.f, 0.5f,
    F6, 0.5f, 0.5f, 0.5f, 1.f, 0.5f, F6, 0.5f, 0.5f, F6,
    F24, F6, F6, 0.25f, 0.5f, 0.25f, F6, 0.5f, 0.5f, F6, F24, F6, 0.25f, F6, F24,
    F120, F24, F24, F12, F6, F12, F12, 0.25f, 0.25f, F12, F24, F6, 0.25f, F6, F24,
    F120, F24, F12, F12, F24, F120};

__global__ __launch_bounds__(512)
__attribute__((amdgpu_waves_per_eu(2, 2)))
void fused_qattn_kernel(
        const float* __restrict__ x, const float* __restrict__ theta,
        const float* __restrict__ W, const float* __restrict__ bias,
        float* __restrict__ out) {
    __shared__ __align__(16) float redL[8][8][168];   // [wave][h][ch*56+i] 43 KB
    __shared__ __align__(16) float MhL[8 * 172];      // [h][ch*56+i], padded
    __shared__ float WtL[16 * 65];
    __shared__ float biasL[64];
    __shared__ float attL[32][17];
    __shared__ float padL[7168];   // 28 KB occupancy shaping: total LDS ~83 KB
                                   // > 80 KB -> only 1 block/CU -> 2 waves/EU
                                   // -> 256-VGPR budget (kills the R13/R14 spill)

    const int tid = threadIdx.x;
    const int b = blockIdx.x >> 5;
    const int chunk = blockIdx.x & 31;
    const int s0 = chunk * 32;

    // never executes (grid is 1-D so blockIdx.y==0); keeps padL allocated
    if (blockIdx.y != 0) {
        ((volatile float*)padL)[tid] = theta[0];
        out[tid] = padL[511 - tid];
    }

    float th[8];
#pragma unroll
    for (int j = 0; j < 8; ++j) th[j] = theta[j];

    // stage projection weights (consumed after 2 barriers in phase C)
    for (int i = tid; i < 1024; i += 512) WtL[(i & 15) * 65 + (i >> 4)] = W[i];
    if (tid < 64) biasL[tid] = bias[tid];

    // ---- phase A: moments (redundant per chunk; 8192 rows / 512 threads) ----
    const int h = tid & 7;
    const int tslot = tid >> 3;                       // 0..63

    float accS[NMONO], accA[NMONO], accB[NMONO];
#pragma unroll
    for (int i = 0; i < NMONO; ++i) { accS[i] = 0.f; accA[i] = 0.f; accB[i] = 0.f; }

#pragma unroll 1
    for (int it = 0; it < 16; ++it) {
        const int t = tslot + 64 * it;
        const float4* xp = (const float4*)(x + ((size_t)(b * NS + t)) * 64 + h * 8);
        float4 lo = xp[0], hi = xp[1];
        float c0 = __cosf(lo.x + th[0]);
        float c1 = __cosf(lo.y + th[1]);
        float c2 = __cosf(lo.z + th[2]);
        float c3 = __cosf(lo.w + th[3]);
        float c4 = __cosf(hi.x + th[4]);
        float c5 = __cosf(hi.y + th[5]);
        float c6 = __cosf(hi.z + th[6]);
        float c7 = __cosf(hi.w + th[7]);
        float k0 = ((c0 * c1) * c2) * c3;
        float k1 = k0 * c4;
        float k2 = k1 * c5;
        float v0 = k2 * c6;
        float v1 = v0 * c7;

        float mono[NMONO];
        mono[0] = 1.f;
        accS[0] += 1.f;
        accA[0] += v0;
        accB[0] += v1;
#pragma unroll
        for (int i = 1; i < NMONO; ++i) {
            float var = (VARI[i] == 0) ? k0 : ((VARI[i] == 1) ? k1 : k2);
            mono[i] = mono[PRED[i]] * var;            // PRED[i] folds to literal
            accS[i] += mono[i];
            accA[i] = fmaf(mono[i], v0, accA[i]);
            accB[i] = fmaf(mono[i], v1, accB[i]);
        }
    }

    // butterfly reduce over same-h lanes (spaced 8 apart: lane bits 3,4,5)
#pragma unroll
    for (int i = 0; i < NMONO; ++i) {
        float a = accS[i];
        a += __shfl_xor(a, 8); a += __shfl_xor(a, 16); a += __shfl_xor(a, 32);
        accS[i] = a;
        float p = accA[i];
        p += __shfl_xor(p, 8); p += __shfl_xor(p, 16); p += __shfl_xor(p, 32);
        accA[i] = p;
        float q = accB[i];
        q += __shfl_xor(q, 8); q += __shfl_xor(q, 16); q += __shfl_xor(q, 32);
        accB[i] = q;
    }

    const int wv = tid >> 6;                          // wave 0..7
    const int l  = tid & 63;
    if (l < 8) {                                      // l == h here
        float* dst = &redL[wv][l][0];
#pragma unroll
        for (int g = 0; g < 14; ++g)
            ((float4*)dst)[g] = make_float4(accS[4*g], accS[4*g+1], accS[4*g+2], accS[4*g+3]);
#pragma unroll
        for (int g = 0; g < 14; ++g)
            ((float4*)(dst + 56))[g] = make_float4(accA[4*g], accA[4*g+1], accA[4*g+2], accA[4*g+3]);
#pragma unroll
        for (int g = 0; g < 14; ++g)
            ((float4*)(dst + 112))[g] = make_float4(accB[4*g], accB[4*g+1], accB[4*g+2], accB[4*g+3]);
    }
    __syncthreads();

    // combine across the 8 waves, fold COEF
    for (int e = tid; e < 8 * 168; e += 512) {
        const int hh = e / 168, j = e - hh * 168;
        float s = 0.f;
#pragma unroll
        for (int ww = 0; ww < 8; ++ww) s += redL[ww][hh][j];
        MhL[hh * 172 + j] = s * COEF[j % 56];
    }
    __syncthreads();

    // ---- phase B: eval 32 s x 8 h rows via 56-dim linear attention ----
    if (tid < 256) {
        const int eh = tid >> 5, sl = tid & 31;
        const int s = s0 + sl;
        const float4* xp = (const float4*)(x + ((size_t)(b * NS + s)) * 64 + eh * 8);
        float4 lo = xp[0], hi = xp[1];
        float c0 = __cosf(lo.x + th[0]);
        float c1 = __cosf(lo.y + th[1]);
        float c2 = __cosf(lo.z + th[2]);
        float c3 = __cosf(lo.w + th[3]);
        float c4 = __cosf(hi.x + th[4]);
        float c5 = __cosf(hi.y + th[5]);
        float c6 = __cosf(hi.z + th[6]);
        float c7 = __cosf(hi.w + th[7]);
        float m1 = c0 * c1;
        float m2 = m1 * c2;
        float m0 = ((c1 * c2) * (c3 * c4)) * ((c5 * c6) * c7);
        float q0 = m0 * 0.125f, q1 = m1 * 0.125f, q2 = m2 * 0.125f;

        float mono[NMONO];
        mono[0] = 1.f;
#pragma unroll
        for (int i = 1; i < NMONO; ++i)
            mono[i] = mono[PRED[i]] * ((VARI[i] == 0) ? q0 : ((VARI[i] == 1) ? q1 : q2));

        const float4* MS = (const float4*)&MhL[eh * 172];
        const float4* MA = (const float4*)&MhL[eh * 172 + 56];
        const float4* MB = (const float4*)&MhL[eh * 172 + 112];
        float aS = 0.f, aA = 0.f, aB = 0.f;
#pragma unroll
        for (int g = 0; g < 14; ++g) {
            float4 ms = MS[g], ma = MA[g], mb = MB[g];
            float p0 = mono[g * 4 + 0], p1 = mono[g * 4 + 1];
            float p2 = mono[g * 4 + 2], p3 = mono[g * 4 + 3];
            aS = fmaf(p0, ms.x, aS); aS = fmaf(p1, ms.y, aS);
            aS = fmaf(p2, ms.z, aS); aS = fmaf(p3, ms.w, aS);
            aA = fmaf(p0, ma.x, aA); aA = fmaf(p1, ma.y, aA);
            aA = fmaf(p2, ma.z, aA); aA = fmaf(p3, ma.w, aA);
            aB = fmaf(p0, mb.x, aB); aB = fmaf(p1, mb.y, aB);
            aB = fmaf(p2, mb.z, aB); aB = fmaf(p3, mb.w, aB);
        }
        float inv = 1.0f / aS;
        attL[sl][2 * eh]     = aA * inv;
        attL[sl][2 * eh + 1] = aB * inv;
    }
    __syncthreads();

    // ---- phase C: projection (32,16) @ W^T + bias -> (32,64) ----
    {
        const int e = tid & 63, r0 = tid >> 6;        // r0 0..7
#pragma unroll
        for (int j = 0; j < 4; ++j) {
            const int row = r0 + 8 * j;               // covers 0..31
            float acc = biasL[e];
#pragma unroll
            for (int jj = 0; jj < 16; ++jj)
                acc = fmaf(attL[row][jj], WtL[jj * 65 + e], acc);
            out[((size_t)(b * NS + s0 + row)) * 64 + e] = acc;
        }
    }
}

extern "C" void kernel_launch(void* const* d_in, const int* in_sizes, int n_in,
                              void* d_out, int out_size, void* d_ws, size_t ws_size,
                              hipStream_t stream) {
    const float* x     = (const float*)d_in[0];
    const float* theta = (const float*)d_in[1];
    const float* W     = (const float*)d_in[2];
    const float* bias  = (const float*)d_in[3];
    float* out = (float*)d_out;

    // one node, no workspace: 256 blocks (= 8 b x 32 s-chunks), 1 block/CU
    fused_qattn_kernel<<<dim3(NB * 32), dim3(512), 0, stream>>>(x, theta, W, bias, out);
}

// Round 4
// 86.813 us; speedup vs baseline: 1.1577x; 1.1502x over previous
//
#include <hip/hip_runtime.h>

#define NB 8
#define NS 1024
#define NH 8
#define NMONO 56    // monomials (a,b,c), a+b+c <= 5, graded order

// ---------------------------------------------------------------------------
// R16: single fused kernel, workspace-free, 256-THREAD BLOCKS (spill fix #3).
// Quantum layer collapsed analytically (verified R3-R11): c_j = cos(x_j+th_j),
//   q = (prod c1..c7, c0c1, c0c1c2)/8, k = (c0..c3, c0..c4, c0..c5),
//   v = (c0..c6, c0..c7).  Linear attention via deg-5 Taylor of e^{q.k}
//   (|q.k|<=0.375, rel err 8e-6): moments M_ch[i] = sum_t mono_i(k) * w_t,
//   w in {1, v0, v1}; att = phi(q).M_v / phi(q).M_1.
// R13/R14/R15 post-mortem: with 512-thread blocks the RA pins the VGPR
//   budget at 128 regardless of launch_bounds 2nd arg, waves_per_eu(2,2),
//   or LDS-forced 1 block/CU (three experiments, VGPR_Count=128 in all,
//   WRITE_SIZE 47 MB = ~45 MB scratch spill of the ~230-reg live set,
//   kernel ~44 us).  Known-good: 256-thread kernels get >128 VGPRs
//   (guide m93: 164 VGPR).  The lever is workgroup shape.
// R16: 256 threads = 4 waves; LDS pad keeps 1 block/CU -> 1 wave/EU ->
//   RA may budget up to 512 VGPRs -> no spill.  Work per block unchanged:
//   32 rows/thread in phase A, butterfly over same-h lanes within wave
//   (xor 8/16/32), 4-wave LDS combine; phase B all 256 threads; phase C
//   8 rows/thread.  #pragma unroll 2 on t-loop for load ILP (1 wave/SIMD).
// Grid: 256 blocks = (b = bid>>5, 32-s chunk = bid&31), 1 block/CU.
// Known-fixed cost outside our control: harness poisons the 256 MiB
//   workspace with a ~44 us fillBuffer INSIDE the timed window each iter.
// ---------------------------------------------------------------------------

// graded enumeration; mono[i] = mono[PRED[i]] * k[VARI[i]] (PRED folds at CT)
constexpr int PRED[NMONO] = {
    0,
    0, 0, 0,
    1, 2, 3, 2, 3, 3,
    4, 5, 6, 7, 8, 9, 7, 8, 9, 9,
    10,11,12,13,14,15,16,17,18,19,16,17,18,19,19,
    20,21,22,23,24,25,26,27,28,29,30,31,32,33,34,30,31,32,33,34,34};
constexpr int VARI[NMONO] = {
    0,
    0, 1, 2,
    0, 0, 0, 1, 1, 2,
    0, 0, 0, 0, 0, 0, 1, 1, 1, 2,
    0, 0, 0, 0, 0, 0, 0, 0, 0, 0, 1, 1, 1, 1, 2,
    0, 0, 0, 0, 0, 0, 0, 0, 0, 0, 0, 0, 0, 0, 0, 1, 1, 1, 1, 1, 2};
#define F6 0.166666666666667f
#define F12 0.0833333333333333f
#define F24 0.0416666666666667f
#define F120 0.00833333333333333f
constexpr float COEF[NMONO] = {          // 1/(a! b! c!)
    1.f,
    1.f, 1.f, 1.f,
    0.5f, 1.f, 1.f, 0.5f, 1.f, 0.5f,
    F6, 0.5f, 0.5f, 0.5f, 1.f, 0.5f, F6, 0.5f, 0.5f, F6,
    F24, F6, F6, 0.25f, 0.5f, 0.25f, F6, 0.5f, 0.5f, F6, F24, F6, 0.25f, F6, F24,
    F120, F24, F24, F12, F6, F12, F12, 0.25f, 0.25f, F12, F24, F6, 0.25f, F6, F24,
    F120, F24, F12, F12, F24, F120};

__global__ __launch_bounds__(256)
__attribute__((amdgpu_waves_per_eu(1)))
void fused_qattn_kernel(
        const float* __restrict__ x, const float* __restrict__ theta,
        const float* __restrict__ W, const float* __restrict__ bias,
        float* __restrict__ out) {
    __shared__ __align__(16) float redL[4][8][168];   // [wave][h][ch*56+i] 21.5 KB
    __shared__ __align__(16) float MhL[8 * 172];      // [h][ch*56+i], padded
    __shared__ float WtL[16 * 65];
    __shared__ float biasL[64];
    __shared__ float attL[32][17];
    __shared__ float padL[12288];  // 48 KB occupancy shaping: total LDS ~82 KB
                                   // > 80 KB -> 1 block/CU -> 1 wave/EU ->
                                   // RA budget up to 512 VGPR (kill the spill)

    const int tid = threadIdx.x;
    const int b = blockIdx.x >> 5;
    const int chunk = blockIdx.x & 31;
    const int s0 = chunk * 32;

    // never executes (grid is 1-D so blockIdx.y==0); keeps padL allocated
    if (blockIdx.y != 0) {
        ((volatile float*)padL)[tid] = theta[0];
        out[tid] = padL[255 - tid];
    }

    float th[8];
#pragma unroll
    for (int j = 0; j < 8; ++j) th[j] = theta[j];

    // stage projection weights (consumed after 2 barriers in phase C)
    for (int i = tid; i < 1024; i += 256) WtL[(i & 15) * 65 + (i >> 4)] = W[i];
    if (tid < 64) biasL[tid] = bias[tid];

    // ---- phase A: moments (redundant per chunk; 8192 rows / 256 threads) ----
    const int h = tid & 7;
    const int tslot = tid >> 3;                       // 0..31

    float accS[NMONO], accA[NMONO], accB[NMONO];
#pragma unroll
    for (int i = 0; i < NMONO; ++i) { accS[i] = 0.f; accA[i] = 0.f; accB[i] = 0.f; }

#pragma unroll 2
    for (int it = 0; it < 32; ++it) {
        const int t = tslot + 32 * it;
        const float4* xp = (const float4*)(x + ((size_t)(b * NS + t)) * 64 + h * 8);
        float4 lo = xp[0], hi = xp[1];
        float c0 = __cosf(lo.x + th[0]);
        float c1 = __cosf(lo.y + th[1]);
        float c2 = __cosf(lo.z + th[2]);
        float c3 = __cosf(lo.w + th[3]);
        float c4 = __cosf(hi.x + th[4]);
        float c5 = __cosf(hi.y + th[5]);
        float c6 = __cosf(hi.z + th[6]);
        float c7 = __cosf(hi.w + th[7]);
        float k0 = ((c0 * c1) * c2) * c3;
        float k1 = k0 * c4;
        float k2 = k1 * c5;
        float v0 = k2 * c6;
        float v1 = v0 * c7;

        float mono[NMONO];
        mono[0] = 1.f;
        accS[0] += 1.f;
        accA[0] += v0;
        accB[0] += v1;
#pragma unroll
        for (int i = 1; i < NMONO; ++i) {
            float var = (VARI[i] == 0) ? k0 : ((VARI[i] == 1) ? k1 : k2);
            mono[i] = mono[PRED[i]] * var;            // PRED[i] folds to literal
            accS[i] += mono[i];
            accA[i] = fmaf(mono[i], v0, accA[i]);
            accB[i] = fmaf(mono[i], v1, accB[i]);
        }
    }

    // butterfly reduce over same-h lanes (spaced 8 apart: lane bits 3,4,5)
#pragma unroll
    for (int i = 0; i < NMONO; ++i) {
        float a = accS[i];
        a += __shfl_xor(a, 8); a += __shfl_xor(a, 16); a += __shfl_xor(a, 32);
        accS[i] = a;
        float p = accA[i];
        p += __shfl_xor(p, 8); p += __shfl_xor(p, 16); p += __shfl_xor(p, 32);
        accA[i] = p;
        float q = accB[i];
        q += __shfl_xor(q, 8); q += __shfl_xor(q, 16); q += __shfl_xor(q, 32);
        accB[i] = q;
    }

    const int wv = tid >> 6;                          // wave 0..3
    const int l  = tid & 63;
    if (l < 8) {                                      // l == h here
        float* dst = &redL[wv][l][0];
#pragma unroll
        for (int g = 0; g < 14; ++g)
            ((float4*)dst)[g] = make_float4(accS[4*g], accS[4*g+1], accS[4*g+2], accS[4*g+3]);
#pragma unroll
        for (int g = 0; g < 14; ++g)
            ((float4*)(dst + 56))[g] = make_float4(accA[4*g], accA[4*g+1], accA[4*g+2], accA[4*g+3]);
#pragma unroll
        for (int g = 0; g < 14; ++g)
            ((float4*)(dst + 112))[g] = make_float4(accB[4*g], accB[4*g+1], accB[4*g+2], accB[4*g+3]);
    }
    __syncthreads();

    // combine across the 4 waves, fold COEF
    for (int e = tid; e < 8 * 168; e += 256) {
        const int hh = e / 168, j = e - hh * 168;
        float s = ((redL[0][hh][j] + redL[1][hh][j])
                 + (redL[2][hh][j] + redL[3][hh][j]));
        MhL[hh * 172 + j] = s * COEF[j % 56];
    }
    __syncthreads();

    // ---- phase B: eval 32 s x 8 h rows via 56-dim linear attention ----
    {
        const int eh = tid >> 5, sl = tid & 31;
        const int s = s0 + sl;
        const float4* xp = (const float4*)(x + ((size_t)(b * NS + s)) * 64 + eh * 8);
        float4 lo = xp[0], hi = xp[1];
        float c0 = __cosf(lo.x + th[0]);
        float c1 = __cosf(lo.y + th[1]);
        float c2 = __cosf(lo.z + th[2]);
        float c3 = __cosf(lo.w + th[3]);
        float c4 = __cosf(hi.x + th[4]);
        float c5 = __cosf(hi.y + th[5]);
        float c6 = __cosf(hi.z + th[6]);
        float c7 = __cosf(hi.w + th[7]);
        float m1 = c0 * c1;
        float m2 = m1 * c2;
        float m0 = ((c1 * c2) * (c3 * c4)) * ((c5 * c6) * c7);
        float q0 = m0 * 0.125f, q1 = m1 * 0.125f, q2 = m2 * 0.125f;

        float mono[NMONO];
        mono[0] = 1.f;
#pragma unroll
        for (int i = 1; i < NMONO; ++i)
            mono[i] = mono[PRED[i]] * ((VARI[i] == 0) ? q0 : ((VARI[i] == 1) ? q1 : q2));

        const float4* MS = (const float4*)&MhL[eh * 172];
        const float4* MA = (const float4*)&MhL[eh * 172 + 56];
        const float4* MB = (const float4*)&MhL[eh * 172 + 112];
        float aS = 0.f, aA = 0.f, aB = 0.f;
#pragma unroll
        for (int g = 0; g < 14; ++g) {
            float4 ms = MS[g], ma = MA[g], mb = MB[g];
            float p0 = mono[g * 4 + 0], p1 = mono[g * 4 + 1];
            float p2 = mono[g * 4 + 2], p3 = mono[g * 4 + 3];
            aS = fmaf(p0, ms.x, aS); aS = fmaf(p1, ms.y, aS);
            aS = fmaf(p2, ms.z, aS); aS = fmaf(p3, ms.w, aS);
            aA = fmaf(p0, ma.x, aA); aA = fmaf(p1, ma.y, aA);
            aA = fmaf(p2, ma.z, aA); aA = fmaf(p3, ma.w, aA);
            aB = fmaf(p0, mb.x, aB); aB = fmaf(p1, mb.y, aB);
            aB = fmaf(p2, mb.z, aB); aB = fmaf(p3, mb.w, aB);
        }
        float inv = 1.0f / aS;
        attL[sl][2 * eh]     = aA * inv;
        attL[sl][2 * eh + 1] = aB * inv;
    }
    __syncthreads();

    // ---- phase C: projection (32,16) @ W^T + bias -> (32,64) ----
    {
        const int e = tid & 63, r0 = tid >> 6;        // r0 0..3
#pragma unroll
        for (int j = 0; j < 8; ++j) {
            const int row = r0 + 4 * j;               // covers 0..31
            float acc = biasL[e];
#pragma unroll
            for (int jj = 0; jj < 16; ++jj)
                acc = fmaf(attL[row][jj], WtL[jj * 65 + e], acc);
            out[((size_t)(b * NS + s0 + row)) * 64 + e] = acc;
        }
    }
}

extern "C" void kernel_launch(void* const* d_in, const int* in_sizes, int n_in,
                              void* d_out, int out_size, void* d_ws, size_t ws_size,
                              hipStream_t stream) {
    const float* x     = (const float*)d_in[0];
    const float* theta = (const float*)d_in[1];
    const float* W     = (const float*)d_in[2];
    const float* bias  = (const float*)d_in[3];
    float* out = (float*)d_out;

    // one node, no workspace: 256 blocks (= 8 b x 32 s-chunks), 1 block/CU
    fused_qattn_kernel<<<dim3(NB * 32), dim3(256), 0, stream>>>(x, theta, W, bias, out);
}

// Round 5
// 84.927 us; speedup vs baseline: 1.1834x; 1.0222x over previous
//
#include <hip/hip_runtime.h>

#define NB 8
#define NS 1024
#define NH 8
#define NMONO 56    // monomials (a,b,c), a+b+c <= 5, graded order

// ---------------------------------------------------------------------------
// R17: single fused kernel, workspace-free, CHANNEL-SPLIT (structural spill fix).
// Quantum layer collapsed analytically (verified R3-R11): c_j = cos(x_j+th_j),
//   q = (prod c1..c7, c0c1, c0c1c2)/8, k = (c0..c3, c0..c4, c0..c5),
//   v = (c0..c6, c0..c7).  Linear attention via deg-5 Taylor of e^{q.k}
//   (|q.k|<=0.375, rel err 8e-6): moments M_ch[i] = sum_t mono_i(k) * w_t,
//   w in {1, v0, v1}; att = phi(q).M_v / phi(q).M_1.
// R13-R16 post-mortem: shared-channel phase A needs 3x56=168 accumulator
//   VGPRs (+~50 temps); the RA pins the budget at 128 for this kernel under
//   every occupancy attribute tried (launch_bounds 2nd arg, waves_per_eu,
//   LDS-forced 1 block/CU, 256-thr blocks) -> ~45 MB scratch traffic
//   (WRITE_SIZE 47 MB vs 2.4 MB output), kernel 35-51 us.
// R17: make the live set fit 128 BY CONSTRUCTION (R12's proven layout):
//   768 threads = 3 channel-groups x 256 threads; each thread accumulates
//   ONE channel's 56 moments.  Channel weight folds into the monomial tree
//   (mono[0] = wch), so per row: 8 cos + 4 chain mul + 55 mul + 56 add.
//   Live set ~110 VGPR < 128.  ~1.5x phase-A instructions vs shared, but
//   no scratch.  Per-thread: 32 rows (tslot = (tid&255)>>3, t = tslot+32*it).
// Reduce: butterfly shfl_xor over same-h lanes (xor 8/16/32) within wave;
//   wave wv = chg*4+wg writes redL[wv][h][56]; combine sums 4 waves/channel.
// Grid: 256 blocks = (b = bid>>5, 32-s chunk = bid&31), 1 block/CU,
//   12 waves/CU.  Phases B (eval, 256 thr) and C (projection) as R16.
// Known-fixed cost outside our control: harness poisons the 256 MiB
//   workspace with a ~40 us fillBuffer INSIDE the timed window each iter.
// ---------------------------------------------------------------------------

// graded enumeration; mono[i] = mono[PRED[i]] * k[VARI[i]] (PRED folds at CT)
constexpr int PRED[NMONO] = {
    0,
    0, 0, 0,
    1, 2, 3, 2, 3, 3,
    4, 5, 6, 7, 8, 9, 7, 8, 9, 9,
    10,11,12,13,14,15,16,17,18,19,16,17,18,19,19,
    20,21,22,23,24,25,26,27,28,29,30,31,32,33,34,30,31,32,33,34,34};
constexpr int VARI[NMONO] = {
    0,
    0, 1, 2,
    0, 0, 0, 1, 1, 2,
    0, 0, 0, 0, 0, 0, 1, 1, 1, 2,
    0, 0, 0, 0, 0, 0, 0, 0, 0, 0, 1, 1, 1, 1, 2,
    0, 0, 0, 0, 0, 0, 0, 0, 0, 0, 0, 0, 0, 0, 0, 1, 1, 1, 1, 1, 2};
#define F6 0.166666666666667f
#define F12 0.0833333333333333f
#define F24 0.0416666666666667f
#define F120 0.00833333333333333f
constexpr float COEF[NMONO] = {          // 1/(a! b! c!)
    1.f,
    1.f, 1.f, 1.f,
    0.5f, 1.f, 1.f, 0.5f, 1.f, 0.5f,
    F6, 0.5f, 0.5f, 0.5f, 1.f, 0.5f, F6, 0.5f, 0.5f, F6,
    F24, F6, F6, 0.25f, 0.5f, 0.25f, F6, 0.5f, 0.5f, F6, F24, F6, 0.25f, F6, F24,
    F120, F24, F24, F12, F6, F12, F12, 0.25f, 0.25f, F12, F24, F6, 0.25f, F6, F24,
    F120, F24, F12, F12, F24, F120};

__global__ __launch_bounds__(768) void fused_qattn_kernel(
        const float* __restrict__ x, const float* __restrict__ theta,
        const float* __restrict__ W, const float* __restrict__ bias,
        float* __restrict__ out) {
    __shared__ __align__(16) float redL[12][8][64];   // [wave][h][mono], 24.6 KB
    __shared__ __align__(16) float MhL[8 * 172];      // [h][ch*56+i], padded
    __shared__ float WtL[16 * 65];
    __shared__ float biasL[64];
    __shared__ float attL[32][17];

    const int tid = threadIdx.x;
    const int b = blockIdx.x >> 5;
    const int chunk = blockIdx.x & 31;
    const int s0 = chunk * 32;

    float th[8];
#pragma unroll
    for (int j = 0; j < 8; ++j) th[j] = theta[j];

    // stage projection weights (consumed after barriers in phase C)
    for (int i = tid; i < 1024; i += 768) WtL[(i & 15) * 65 + (i >> 4)] = W[i];
    if (tid < 64) biasL[tid] = bias[tid];

    // ---- phase A: moments; thread = (chg = tid>>8, h = tid&7, tslot) ----
    const int chg = tid >> 8;                         // 0: sum, 1: v0, 2: v1
    const int tg  = tid & 255;
    const int h = tg & 7;
    const int tslot = tg >> 3;                        // 0..31

    float acc[NMONO];
#pragma unroll
    for (int i = 0; i < NMONO; ++i) acc[i] = 0.f;

#pragma unroll 2
    for (int it = 0; it < 32; ++it) {
        const int t = tslot + 32 * it;
        const float4* xp = (const float4*)(x + ((size_t)(b * NS + t)) * 64 + h * 8);
        float4 lo = xp[0], hi = xp[1];
        float c0 = __cosf(lo.x + th[0]);
        float c1 = __cosf(lo.y + th[1]);
        float c2 = __cosf(lo.z + th[2]);
        float c3 = __cosf(lo.w + th[3]);
        float c4 = __cosf(hi.x + th[4]);
        float c5 = __cosf(hi.y + th[5]);
        float c6 = __cosf(hi.z + th[6]);
        float c7 = __cosf(hi.w + th[7]);
        float k0 = ((c0 * c1) * c2) * c3;
        float k1 = k0 * c4;
        float k2 = k1 * c5;
        float v0 = k2 * c6;
        float v1 = v0 * c7;
        float wch = (chg == 0) ? 1.f : ((chg == 1) ? v0 : v1);

        // weight folds into the tree: mono[i] here is true mono * wch
        float mono[NMONO];
        mono[0] = wch;
        acc[0] += wch;
#pragma unroll
        for (int i = 1; i < NMONO; ++i) {
            float var = (VARI[i] == 0) ? k0 : ((VARI[i] == 1) ? k1 : k2);
            mono[i] = mono[PRED[i]] * var;            // PRED[i] folds to literal
            acc[i] += mono[i];
        }
    }

    // butterfly reduce over same-h lanes (spaced 8 apart: lane bits 3,4,5)
#pragma unroll
    for (int i = 0; i < NMONO; ++i) {
        float a = acc[i];
        a += __shfl_xor(a, 8); a += __shfl_xor(a, 16); a += __shfl_xor(a, 32);
        acc[i] = a;
    }

    const int wv = tid >> 6;                          // wave 0..11 = chg*4+wg
    const int l  = tid & 63;
    if (l < 8) {                                      // l == h here
        float* dst = &redL[wv][l][0];
#pragma unroll
        for (int g = 0; g < 14; ++g)
            ((float4*)dst)[g] = make_float4(acc[4*g], acc[4*g+1], acc[4*g+2], acc[4*g+3]);
    }
    __syncthreads();

    // combine the 4 waves of each channel group, fold COEF
    for (int e = tid; e < 8 * 168; e += 768) {
        const int hh = e / 168, j = e - hh * 168;
        const int c = j / 56, i = j - c * 56;
        float s = ((redL[c * 4 + 0][hh][i] + redL[c * 4 + 1][hh][i])
                 + (redL[c * 4 + 2][hh][i] + redL[c * 4 + 3][hh][i]));
        MhL[hh * 172 + j] = s * COEF[i];
    }
    __syncthreads();

    // ---- phase B: eval 32 s x 8 h rows via 56-dim linear attention ----
    if (tid < 256) {
        const int eh = tid >> 5, sl = tid & 31;
        const int s = s0 + sl;
        const float4* xp = (const float4*)(x + ((size_t)(b * NS + s)) * 64 + eh * 8);
        float4 lo = xp[0], hi = xp[1];
        float c0 = __cosf(lo.x + th[0]);
        float c1 = __cosf(lo.y + th[1]);
        float c2 = __cosf(lo.z + th[2]);
        float c3 = __cosf(lo.w + th[3]);
        float c4 = __cosf(hi.x + th[4]);
        float c5 = __cosf(hi.y + th[5]);
        float c6 = __cosf(hi.z + th[6]);
        float c7 = __cosf(hi.w + th[7]);
        float m1 = c0 * c1;
        float m2 = m1 * c2;
        float m0 = ((c1 * c2) * (c3 * c4)) * ((c5 * c6) * c7);
        float q0 = m0 * 0.125f, q1 = m1 * 0.125f, q2 = m2 * 0.125f;

        float mono[NMONO];
        mono[0] = 1.f;
#pragma unroll
        for (int i = 1; i < NMONO; ++i)
            mono[i] = mono[PRED[i]] * ((VARI[i] == 0) ? q0 : ((VARI[i] == 1) ? q1 : q2));

        const float4* MS = (const float4*)&MhL[eh * 172];
        const float4* MA = (const float4*)&MhL[eh * 172 + 56];
        const float4* MB = (const float4*)&MhL[eh * 172 + 112];
        float aS = 0.f, aA = 0.f, aB = 0.f;
#pragma unroll
        for (int g = 0; g < 14; ++g) {
            float4 ms = MS[g], ma = MA[g], mb = MB[g];
            float p0 = mono[g * 4 + 0], p1 = mono[g * 4 + 1];
            float p2 = mono[g * 4 + 2], p3 = mono[g * 4 + 3];
            aS = fmaf(p0, ms.x, aS); aS = fmaf(p1, ms.y, aS);
            aS = fmaf(p2, ms.z, aS); aS = fmaf(p3, ms.w, aS);
            aA = fmaf(p0, ma.x, aA); aA = fmaf(p1, ma.y, aA);
            aA = fmaf(p2, ma.z, aA); aA = fmaf(p3, ma.w, aA);
            aB = fmaf(p0, mb.x, aB); aB = fmaf(p1, mb.y, aB);
            aB = fmaf(p2, mb.z, aB); aB = fmaf(p3, mb.w, aB);
        }
        float inv = 1.0f / aS;
        attL[sl][2 * eh]     = aA * inv;
        attL[sl][2 * eh + 1] = aB * inv;
    }
    __syncthreads();

    // ---- phase C: projection (32,16) @ W^T + bias -> (32,64) ----
    if (tid < 256) {
        const int e = tid & 63, r0 = tid >> 6;        // r0 0..3
#pragma unroll
        for (int j = 0; j < 8; ++j) {
            const int row = r0 + 4 * j;               // covers 0..31
            float acc2 = biasL[e];
#pragma unroll
            for (int jj = 0; jj < 16; ++jj)
                acc2 = fmaf(attL[row][jj], WtL[jj * 65 + e], acc2);
            out[((size_t)(b * NS + s0 + row)) * 64 + e] = acc2;
        }
    }
}

extern "C" void kernel_launch(void* const* d_in, const int* in_sizes, int n_in,
                              void* d_out, int out_size, void* d_ws, size_t ws_size,
                              hipStream_t stream) {
    const float* x     = (const float*)d_in[0];
    const float* theta = (const float*)d_in[1];
    const float* W     = (const float*)d_in[2];
    const float* bias  = (const float*)d_in[3];
    float* out = (float*)d_out;

    // one node, no workspace: 256 blocks (= 8 b x 32 s-chunks), 1 block/CU
    fused_qattn_kernel<<<dim3(NB * 32), dim3(768), 0, stream>>>(x, theta, W, bias, out);
}